// Round 3
// baseline (143.449 us; speedup 1.0000x reference)
//
#include <hip/hip_runtime.h>

// Problem constants (nb=16, k=11, ps=10, with_padding=1, rgb 1x3x2048x2048 f32)
constexpr int H   = 2048;
constexpr int W   = 2048;
constexpr int NB  = 16;
constexpr int K   = 11;
constexpr int PS  = 10;
constexpr int PAD = (K - 1) / 2;                 // 5
constexpr int HO  = (H + 2 * PAD - K) / PS + 1;  // 205
constexpr int WO  = (W + 2 * PAD - K) / PS + 1;  // 205
constexpr int PSP = PS + 1;                      // 11 (padded block pitch)
constexpr int OH  = HO * PSP;                    // 2255
constexpr int OW  = WO * PSP;                    // 2255

constexpr int TW  = 4;                 // 4x4 windows per block
constexpr int R   = TW * PS + K - 1;   // 41x41 pixel region per tile
constexpr int NPX = R * R;             // 1681
constexpr int OB  = TW * PSP;          // 44: output span per block per axis
constexpr int NWRITE = 3 * OB * OB;    // 5808 output elements per block

// Fused kernel: one block = 4x4 window tile.
// Phase A: stage 41x41 rgb region into LDS (coalesced; each pixel fetched from
//   HBM once). 16 threads/window, pixels cached in registers. Packed-u64
//   histogram + shfl_xor(16) reduce + first-tie-wins argmax + conditional sums.
//   Results broadcast via 192 B of LDS.
// Phase B: all 256 threads write the block's 44x44x3 output region directly
//   (10x10 replicated value + zero pad row/col per window). Runs of 44
//   consecutive floats; L2 merges partial lines, HBM writes stay minimal.
__global__ __launch_bounds__(256) void pixel_effect_kernel(const float* __restrict__ rgb,
                                                           float* __restrict__ out) {
    __shared__ float ls_r[NPX];
    __shared__ float ls_g[NPX];
    __shared__ float ls_b[NPX];
    __shared__ float wval[3][TW * TW];   // per-window rgb result

    int tid = threadIdx.x;
    int wy0 = blockIdx.y * TW;
    int wx0 = blockIdx.x * TW;
    int gy0 = wy0 * PS - PAD;
    int gx0 = wx0 * PS - PAD;

    const float* __restrict__ rp = rgb;
    const float* __restrict__ gp = rgb + H * W;
    const float* __restrict__ bp = rgb + 2 * H * W;

    // ---- Phase A1: stage tile into LDS (coalesced) ----
    for (int p = tid; p < NPX; p += 256) {
        int j = p / R, i = p - j * R;
        int y = gy0 + j, x = gx0 + i;
        float r, g, b;
        if ((unsigned)y < (unsigned)H && (unsigned)x < (unsigned)W) {
            long o = (long)y * W + x;
            r = rp[o]; g = gp[o]; b = bp[o];
        } else {
            r = g = b = 1.0e9f;   // sentinel: bin idx lands far outside [0,16)
        }
        ls_r[p] = r; ls_g[p] = g; ls_b[p] = b;
    }
    __syncthreads();

    int wid = tid >> 4;             // 0..15  local window
    int sub = tid & 15;             // 0..15  lane within window
    int wly = wid >> 2, wlx = wid & 3;
    bool valid = (wy0 + wly < HO) && (wx0 + wlx < WO);
    int base = (wly * PS) * R + (wlx * PS);

    // ---- Phase A2: per-window histogram from register-cached pixels ----
    float cr[8], cg[8], cb[8];
    int   ci[8];
    unsigned long long lo = 0ull, hi = 0ull;
    #pragma unroll
    for (int t = 0; t < 8; ++t) {
        int p = sub + 16 * t;       // t<7: p<121 always; t==7 valid iff sub<9
        float r = 0.f, g = 0.f, b = 0.f;
        int idx = 9999;
        if (p < K * K) {
            int j = p / K, i = p - j * K;
            int addr = base + j * R + i;
            r = ls_r[addr]; g = ls_g[addr]; b = ls_b[addr];
            float mean = (r + g + b) / 3.0f;      // matches np.mean fp32
            idx = (int)(mean * 0.0625f);          // exact pow2: mean/256*16
        }
        cr[t] = r; cg[t] = g; cb[t] = b; ci[t] = idx;
        if ((unsigned)idx < 8u)       lo += 1ull << (idx * 8);
        else if ((unsigned)idx < 16u) hi += 1ull << ((idx - 8) * 8);
    }
    #pragma unroll
    for (int s = 1; s < 16; s <<= 1) {
        lo += __shfl_xor(lo, s, 16);
        hi += __shfl_xor(hi, s, 16);
    }

    // argmax over 16 bins, first-tie-wins (jnp.argmax semantics)
    int best = 0;
    int bestc = (int)(lo & 0xffull);
    #pragma unroll
    for (int b = 1; b < NB; ++b) {
        unsigned long long wsel = (b < 8) ? lo : hi;
        int c = (int)((wsel >> ((b & 7) * 8)) & 0xffull);
        if (c > bestc) { bestc = c; best = b; }
    }

    // conditional sums (register-only)
    float sr = 0.f, sg = 0.f, sb = 0.f;
    #pragma unroll
    for (int t = 0; t < 8; ++t) {
        if (ci[t] == best) { sr += cr[t]; sg += cg[t]; sb += cb[t]; }
    }
    #pragma unroll
    for (int s = 1; s < 16; s <<= 1) {
        sr += __shfl_xor(sr, s, 16);
        sg += __shfl_xor(sg, s, 16);
        sb += __shfl_xor(sb, s, 16);
    }

    if (sub == 0) {
        float inv = 1.0f;
        float cm = (float)bestc;          // > 0 always (>= 36 in-bounds px)
        wval[0][wid] = sr / cm;
        wval[1][wid] = sg / cm;
        wval[2][wid] = sb / cm;
        (void)inv;
    }
    __syncthreads();

    // ---- Phase B: write the 44x44x3 output region ----
    for (int q = tid; q < NWRITE; q += 256) {
        int ch  = q / (OB * OB);
        int rem = q - ch * (OB * OB);
        int row = rem / OB;               // 0..43 within block region
        int col = rem - row * OB;
        int wly2 = row / PSP, iy = row - wly2 * PSP;
        int wlx2 = col / PSP, ix = col - wlx2 * PSP;
        int wy = wy0 + wly2, wx = wx0 + wlx2;
        if (wy >= HO || wx >= WO) continue;   // edge blocks: window out of range
        float v = 0.0f;
        if (iy != PS && ix != PS) v = wval[ch][wly2 * TW + wlx2];
        long oy = (long)wy * PSP + iy;
        long ox = (long)wx * PSP + ix;
        out[(long)ch * OH * OW + oy * OW + ox] = v;
    }
}

extern "C" void kernel_launch(void* const* d_in, const int* in_sizes, int n_in,
                              void* d_out, int out_size, void* d_ws, size_t ws_size,
                              hipStream_t stream) {
    const float* rgb = (const float*)d_in[0];
    float* out = (float*)d_out;

    dim3 grid((WO + TW - 1) / TW, (HO + TW - 1) / TW);   // 52 x 52 = 2704 blocks
    pixel_effect_kernel<<<grid, 256, 0, stream>>>(rgb, out);
}

// Round 4
// 123.348 us; speedup vs baseline: 1.1630x; 1.1630x over previous
//
#include <hip/hip_runtime.h>

// Problem constants (nb=16, k=11, ps=10, with_padding=1, rgb 1x3x2048x2048 f32)
constexpr int H   = 2048;
constexpr int W   = 2048;
constexpr int NB  = 16;
constexpr int K   = 11;
constexpr int PS  = 10;
constexpr int PAD = (K - 1) / 2;                 // 5
constexpr int HO  = (H + 2 * PAD - K) / PS + 1;  // 205
constexpr int WO  = (W + 2 * PAD - K) / PS + 1;  // 205
constexpr int PSP = PS + 1;                      // 11
constexpr int OH  = HO * PSP;                    // 2255
constexpr int OW  = WO * PSP;                    // 2255

constexpr int TW  = 4;                 // 4x4 windows per block
constexpr int R   = TW * PS + K - 1;   // 41 rows/cols of pixels per tile
constexpr int NF4 = 12;                // aligned float4 slots per row (covers 41 cols, gx0%4==3)
constexpr int LP  = NF4 * 4;           // 48: LDS row pitch (float4-aligned)
constexpr int NSLOT = R * NF4;         // 492 float4 slots per channel

// Kernel 1: one block = 4x4 window tile. Stage 41x48 (padded) rgb region into
// LDS with ALIGNED float4 loads (gx0 = 40*bx-5 is always ==3 mod 4, so the
// 12-float4 footprint [gx0-3, gx0+45) covers the tile; OOB float4s get the
// sentinel). 16 threads/window, pixels cached in regs; packed-u64 histogram +
// shfl_xor(16) reduce + first-tie-wins argmax + conditional sums.
__global__ __launch_bounds__(256) void window_kernel(const float* __restrict__ rgb,
                                                     float* __restrict__ val) {
    __shared__ float ls_r[R * LP];
    __shared__ float ls_g[R * LP];
    __shared__ float ls_b[R * LP];

    int tid = threadIdx.x;
    int wy0 = blockIdx.y * TW;
    int wx0 = blockIdx.x * TW;
    int gy0 = wy0 * PS - PAD;
    int gx0 = wx0 * PS - PAD;          // == 3 (mod 4) for every block
    int f0  = gx0 >> 2;                // arithmetic shift = floor div (gx0 may be -5)

    const float* __restrict__ rp = rgb;
    const float* __restrict__ gp = rgb + H * W;
    const float* __restrict__ bp = rgb + 2 * H * W;

    // ---- stage tile into LDS: aligned float4 loads, each HBM byte read once ----
    const float4 SENT = make_float4(1.0e9f, 1.0e9f, 1.0e9f, 1.0e9f);
    for (int s = tid; s < NSLOT; s += 256) {
        int row = s / NF4;             // 0..40
        int f   = s - row * NF4;       // 0..11
        int y   = gy0 + row;
        int fg  = f0 + f;              // global float4 index along x
        float4 r4 = SENT, g4 = SENT, b4 = SENT;
        if ((unsigned)y < (unsigned)H && (unsigned)fg < (unsigned)(W / 4)) {
            long o = (long)y * W + (fg << 2);
            r4 = *(const float4*)(rp + o);
            g4 = *(const float4*)(gp + o);
            b4 = *(const float4*)(bp + o);
        }
        int la = row * LP + (f << 2);  // 16B-aligned LDS address
        *(float4*)(ls_r + la) = r4;
        *(float4*)(ls_g + la) = g4;
        *(float4*)(ls_b + la) = b4;
    }
    __syncthreads();

    int wid = tid >> 4;                // 0..15 local window
    int sub = tid & 15;                // 0..15 lane within window
    int wly = wid >> 2, wlx = wid & 3;
    int wy = wy0 + wly, wx = wx0 + wlx;
    bool valid = (wy < HO) && (wx < WO);
    // tile col c maps to LDS index c+3 (footprint starts at gx0-3)
    int base = (wly * PS) * LP + (wlx * PS) + 3;

    // ---- pass 1: load my ~8 pixels, cache in regs, packed histogram ----
    float cr[8], cg[8], cb[8];
    int   ci[8];
    unsigned long long lo = 0ull, hi = 0ull;
    #pragma unroll
    for (int t = 0; t < 8; ++t) {
        int p = sub + 16 * t;          // t<7: p<121 always; t==7 valid iff sub<9
        float r = 0.f, g = 0.f, b = 0.f;
        int idx = 9999;
        if (p < K * K) {
            int j = p / K, i = p - j * K;
            int addr = base + j * LP + i;
            r = ls_r[addr]; g = ls_g[addr]; b = ls_b[addr];
            float mean = (r + g + b) / 3.0f;     // matches np.mean fp32
            idx = (int)(mean * 0.0625f);         // exact pow2: mean/256*16
        }
        cr[t] = r; cg[t] = g; cb[t] = b; ci[t] = idx;
        if ((unsigned)idx < 8u)       lo += 1ull << (idx * 8);
        else if ((unsigned)idx < 16u) hi += 1ull << ((idx - 8) * 8);
    }
    #pragma unroll
    for (int s = 1; s < 16; s <<= 1) {
        lo += __shfl_xor(lo, s, 16);
        hi += __shfl_xor(hi, s, 16);
    }

    // ---- argmax over 16 bins, first-tie-wins (jnp.argmax) ----
    int best = 0;
    int bestc = (int)(lo & 0xffull);
    #pragma unroll
    for (int b = 1; b < NB; ++b) {
        unsigned long long wsel = (b < 8) ? lo : hi;
        int c = (int)((wsel >> ((b & 7) * 8)) & 0xffull);
        if (c > bestc) { bestc = c; best = b; }
    }

    // ---- pass 2: register-only conditional sums ----
    float sr = 0.f, sg = 0.f, sb = 0.f;
    #pragma unroll
    for (int t = 0; t < 8; ++t) {
        if (ci[t] == best) { sr += cr[t]; sg += cg[t]; sb += cb[t]; }
    }
    #pragma unroll
    for (int s = 1; s < 16; s <<= 1) {
        sr += __shfl_xor(sr, s, 16);
        sg += __shfl_xor(sg, s, 16);
        sb += __shfl_xor(sb, s, 16);
    }

    if (sub == 0 && valid) {
        float cm = (float)bestc;       // > 0 always (>= 36 in-bounds px)
        int o = wy * WO + wx;
        val[o]               = sr / cm;
        val[HO * WO + o]     = sg / cm;
        val[2 * HO * WO + o] = sb / cm;
    }
}

// Kernel 2: one block per output row (3*2255 rows). Row -> (channel, by, iy)
// decomposed once (block-uniform). val row staged in LDS; per element a single
// magic-div by 11 + select; stores are full contiguous rows (exact 61 MB).
__global__ __launch_bounds__(256) void write_kernel(const float* __restrict__ val,
                                                    float* __restrict__ out) {
    int row = blockIdx.x;              // 0 .. 3*OH-1
    int c   = row / OH;
    int y   = row - c * OH;
    int by  = y / PSP;
    int iy  = y - by * PSP;

    __shared__ float lv[WO];
    if (threadIdx.x < WO) lv[threadIdx.x] = val[c * HO * WO + by * WO + threadIdx.x];
    __syncthreads();

    bool zrow = (iy == PS);
    long base = (long)row * OW;
    for (int x = threadIdx.x; x < OW; x += 256) {
        int bx = (int)((unsigned)x / (unsigned)PSP);   // compiler magic-mul
        int ix = x - bx * PSP;
        float v = (zrow || ix == PS) ? 0.0f : lv[bx];
        out[base + x] = v;
    }
}

extern "C" void kernel_launch(void* const* d_in, const int* in_sizes, int n_in,
                              void* d_out, int out_size, void* d_ws, size_t ws_size,
                              hipStream_t stream) {
    const float* rgb = (const float*)d_in[0];
    float* val = (float*)d_ws;         // 3*205*205 floats = 504,300 B scratch
    float* out = (float*)d_out;

    dim3 grid1((WO + TW - 1) / TW, (HO + TW - 1) / TW);   // 52 x 52 = 2704
    window_kernel<<<grid1, 256, 0, stream>>>(rgb, val);

    write_kernel<<<3 * OH, 256, 0, stream>>>(val, out);   // 6765 blocks
}